// Round 1
// baseline (66.409 us; speedup 1.0000x reference)
//
#include <hip/hip_runtime.h>
#include <math.h>

#define UNITS  512
#define BATCH  32
#define SEQ    4096
#define CHUNKS 32
#define RPC    (SEQ / CHUNKS)   // 128 rows per chunk

// workspace layout (float offsets)
#define OFF_UV    0                       // 512
#define OFF_WV    512                     // 512
#define OFF_PBIAS 1024                    // 32
#define OFF_PSUM  2048                    // BATCH*CHUNKS = 1024
#define OFF_P     4096                    // BATCH*SEQ = 131072
#define OFF_PCTX  (4096 + BATCH*SEQ)      // BATCH*CHUNKS*UNITS = 524288
// total ~660K floats = 2.64 MB

__device__ inline float wave_reduce_add(float v) {
#pragma unroll
    for (int off = 32; off >= 1; off >>= 1) v += __shfl_xor(v, off);
    return v;
}

__device__ inline float dot8(float4 a, float4 b, float4 u0, float4 u1) {
    return a.x*u0.x + a.y*u0.y + a.z*u0.z + a.w*u0.w
         + b.x*u1.x + b.y*u1.y + b.z*u1.z + b.w*u1.w;
}

// K0: uv[u] = sum_v U_w[u,v]*V_w[v];  wv[u] = sum_v W_w[u,v]*V_w[v]
__global__ __launch_bounds__(256) void k_uvwv(const float* __restrict__ Ww,
                                              const float* __restrict__ Uw,
                                              const float* __restrict__ Vw,
                                              float* __restrict__ ws) {
    int tid = threadIdx.x, wave = tid >> 6, lane = tid & 63;
    float4 v0 = *(const float4*)(Vw + lane * 8);
    float4 v1 = *(const float4*)(Vw + lane * 8 + 4);
    int rowbase = blockIdx.x * 16;
    for (int i = wave; i < 16; i += 4) {
        int u = rowbase + i;
        const float* ur = Uw + (size_t)u * UNITS + lane * 8;
        float4 a = *(const float4*)ur;
        float4 b = *(const float4*)(ur + 4);
        float d = wave_reduce_add(dot8(a, b, v0, v1));
        if (lane == 0) ws[OFF_UV + u] = d;
        const float* wr = Ww + (size_t)u * UNITS + lane * 8;
        a = *(const float4*)wr;
        b = *(const float4*)(wr + 4);
        d = wave_reduce_add(dot8(a, b, v0, v1));
        if (lane == 0) ws[OFF_WV + u] = d;
    }
}

// K1: pbias[b] = s_prev[b,:]·wv + (W_b+U_b)·V_w + V_b
__global__ __launch_bounds__(256) void k_pbias(const float* __restrict__ s_prev,
                                               const float* __restrict__ Wb,
                                               const float* __restrict__ Ub,
                                               const float* __restrict__ Vw,
                                               const float* __restrict__ Vb,
                                               float* __restrict__ ws) {
    __shared__ float red[256];
    __shared__ float cb_sh;
    int tid = threadIdx.x;
    float cb = 0.f;
    for (int v = tid; v < UNITS; v += 256) cb += (Wb[v] + Ub[v]) * Vw[v];
    red[tid] = cb;
    __syncthreads();
    for (int s = 128; s > 0; s >>= 1) {
        if (tid < s) red[tid] += red[tid + s];
        __syncthreads();
    }
    if (tid == 0) cb_sh = red[0] + Vb[0];
    __syncthreads();
    float cbv = cb_sh;
    int wave = tid >> 6, lane = tid & 63;
    float4 w0 = *(const float4*)(ws + OFF_WV + lane * 8);
    float4 w1 = *(const float4*)(ws + OFF_WV + lane * 8 + 4);
    for (int b = wave; b < BATCH; b += 4) {
        const float* sp = s_prev + (size_t)b * UNITS + lane * 8;
        float4 a = *(const float4*)sp;
        float4 c = *(const float4*)(sp + 4);
        float d = wave_reduce_add(dot8(a, c, w0, w1));
        if (lane == 0) ws[OFF_PBIAS + b] = d + cbv;
    }
}

// K2: stream hidden_states once. Per (b,chunk): p=exp(tanh(h·uv+pbias)),
// partial sum of p, partial context sum of p*h.
__global__ __launch_bounds__(256) void k_main(const float* __restrict__ h,
                                              float* __restrict__ ws) {
    int chunk = blockIdx.x, b = blockIdx.y;
    int tid = threadIdx.x, wave = tid >> 6, lane = tid & 63;

    float4 u0 = *(const float4*)(ws + OFF_UV + lane * 8);
    float4 u1 = *(const float4*)(ws + OFF_UV + lane * 8 + 4);
    float pb = ws[OFF_PBIAS + b];

    float4 acc0 = make_float4(0.f, 0.f, 0.f, 0.f);
    float4 acc1 = make_float4(0.f, 0.f, 0.f, 0.f);
    float zs = 0.f;

    const float* hb = h + ((size_t)b * SEQ + (size_t)chunk * RPC) * UNITS + lane * 8;
    float* pout = ws + OFF_P + (size_t)b * SEQ + (size_t)chunk * RPC;

    // each wave: rows r and r+4 per iteration (2 rows in flight)
    for (int r = wave; r < RPC; r += 8) {
        const float* r0 = hb + (size_t)r * UNITS;
        const float* r1 = hb + (size_t)(r + 4) * UNITS;
        float4 a0 = *(const float4*)r0;
        float4 b0 = *(const float4*)(r0 + 4);
        float4 a1 = *(const float4*)r1;
        float4 b1 = *(const float4*)(r1 + 4);

        float d0 = dot8(a0, b0, u0, u1);
        float d1 = dot8(a1, b1, u0, u1);
#pragma unroll
        for (int off = 32; off >= 1; off >>= 1) {
            d0 += __shfl_xor(d0, off);
            d1 += __shfl_xor(d1, off);
        }
        float e0 = tanhf(d0 + pb);
        float e1 = tanhf(d1 + pb);
        float w0 = __expf(e0);
        float w1 = __expf(e1);
        if (lane == 0) { pout[r] = w0; pout[r + 4] = w1; }
        zs += w0 + w1;
        acc0.x += w0 * a0.x + w1 * a1.x;
        acc0.y += w0 * a0.y + w1 * a1.y;
        acc0.z += w0 * a0.z + w1 * a1.z;
        acc0.w += w0 * a0.w + w1 * a1.w;
        acc1.x += w0 * b0.x + w1 * b1.x;
        acc1.y += w0 * b0.y + w1 * b1.y;
        acc1.z += w0 * b0.z + w1 * b1.z;
        acc1.w += w0 * b0.w + w1 * b1.w;
    }

    __shared__ float lctx[4][UNITS];
    __shared__ float lsum[4];
    *(float4*)&lctx[wave][lane * 8]     = acc0;
    *(float4*)&lctx[wave][lane * 8 + 4] = acc1;
    if (lane == 0) lsum[wave] = zs;
    __syncthreads();

    float* pc = ws + OFF_PCTX + ((size_t)(b * CHUNKS + chunk)) * UNITS;
    for (int col = tid; col < UNITS; col += 256)
        pc[col] = lctx[0][col] + lctx[1][col] + lctx[2][col] + lctx[3][col];
    if (tid == 0)
        ws[OFF_PSUM + b * CHUNKS + chunk] = lsum[0] + lsum[1] + lsum[2] + lsum[3];
}

// K3: per batch: Z = sum partials; context = (sum pctx)/Z; weights = p/Z
__global__ __launch_bounds__(256) void k_final(const float* __restrict__ ws,
                                               float* __restrict__ out) {
    int b = blockIdx.x, tid = threadIdx.x;
    __shared__ float zsh;
    if (tid == 0) {
        float z = 0.f;
        for (int c = 0; c < CHUNKS; c++) z += ws[OFF_PSUM + b * CHUNKS + c];
        zsh = 1.0f / z;
    }
    __syncthreads();
    float rz = zsh;

    for (int col = tid; col < UNITS; col += 256) {
        float s = 0.f;
#pragma unroll
        for (int c = 0; c < CHUNKS; c++)
            s += ws[OFF_PCTX + (size_t)(b * CHUNKS + c) * UNITS + col];
        out[(size_t)b * UNITS + col] = s * rz;
    }

    const float* p = ws + OFF_P + (size_t)b * SEQ;
    float* wout = out + (size_t)BATCH * UNITS + (size_t)b * SEQ;
    for (int s = tid; s < SEQ; s += 256) wout[s] = p[s] * rz;
}

extern "C" void kernel_launch(void* const* d_in, const int* in_sizes, int n_in,
                              void* d_out, int out_size, void* d_ws, size_t ws_size,
                              hipStream_t stream) {
    (void)in_sizes; (void)n_in; (void)out_size; (void)ws_size;
    const float* s_prev = (const float*)d_in[0];
    const float* h      = (const float*)d_in[1];
    const float* Ww     = (const float*)d_in[2];
    const float* Wb     = (const float*)d_in[3];
    const float* Uw     = (const float*)d_in[4];
    const float* Ub     = (const float*)d_in[5];
    const float* Vw     = (const float*)d_in[6];
    const float* Vb     = (const float*)d_in[7];
    float* out = (float*)d_out;
    float* ws  = (float*)d_ws;

    hipLaunchKernelGGL(k_uvwv,  dim3(32),            dim3(256), 0, stream, Ww, Uw, Vw, ws);
    hipLaunchKernelGGL(k_pbias, dim3(1),             dim3(256), 0, stream, s_prev, Wb, Ub, Vw, Vb, ws);
    hipLaunchKernelGGL(k_main,  dim3(CHUNKS, BATCH), dim3(256), 0, stream, h, ws);
    hipLaunchKernelGGL(k_final, dim3(BATCH),         dim3(256), 0, stream, ws, out);
}